// Round 1
// baseline (5275.350 us; speedup 1.0000x reference)
//
#include <hip/hip_runtime.h>
#include <math.h>

#define NB 16
#define NHH 128
#define NWW 128
#define NPOS (NB*NHH*NWW)      // 262144
#define NSTEPS 5

// float offsets in workspace
#define OFF_STATE   0
#define OFF_HIDDEN  (NPOS*64)                 // 16777216
#define OFF_WUP1    (OFF_HIDDEN + NPOS*64)    // 33554432
#define OFF_WUP2    (OFF_WUP1 + 9*64*64)
#define OFF_WTAU    (OFF_WUP2 + 64*64)
#define OFF_CBSQ    (OFF_WTAU + 64*64)
#define OFF_PART    (OFF_CBSQ + 512)
#define OFF_LOSS    (OFF_PART + 4096)

// ---------------- prep: weight transposes + codebook norms + loss init ----------------
__global__ void prep_kernel(const float* __restrict__ up1_w, const float* __restrict__ up2_w,
                            const float* __restrict__ tau_w, const float* __restrict__ cb,
                            float* __restrict__ ws) {
  int id = blockIdx.x * 256 + threadIdx.x;
  float* wT1  = ws + OFF_WUP1;
  float* wT2  = ws + OFF_WUP2;
  float* wTt  = ws + OFF_WTAU;
  float* cbsq = ws + OFF_CBSQ;
  if (id < 36864) {
    int tap = id / 4096; int r = id - tap * 4096; int ci = r >> 6; int co = r & 63;
    wT1[id] = up1_w[(co * 64 + ci) * 9 + tap];           // OIHW -> [tap][ci][co]
  } else if (id < 36864 + 4096) {
    int j = id - 36864; int ci = j >> 6; int co = j & 63;
    wT2[j] = up2_w[co * 64 + ci];
  } else if (id < 36864 + 8192) {
    int j = id - 36864 - 4096; int ci = j >> 6; int co = j & 63;
    wTt[j] = tau_w[co * 64 + ci];
  } else if (id < 36864 + 8192 + 512) {
    int k = id - 36864 - 8192;
    float s = 0.f;
    for (int c = 0; c < 64; ++c) { float v = cb[k * 64 + c]; s += v * v; }
    cbsq[k] = s;
  } else if (id == 36864 + 8192 + 512) {
    ws[OFF_LOSS] = 0.f;
  }
}

// ---------------- stem: conv3x3 1->64 + relu, writes NHWC state ----------------
__global__ void stem_kernel(const float* __restrict__ x, const float* __restrict__ stem_w,
                            const float* __restrict__ stem_b, float* __restrict__ state) {
  int n = blockIdx.x * 256 + threadIdx.x;
  int pos = n >> 6, c = n & 63;
  int b = pos >> 14, hw = pos & 16383, h = hw >> 7, w = hw & 127;
  const float* xb = x + b * 16384;
  float acc = stem_b[c];
  #pragma unroll
  for (int ky = 0; ky < 3; ++ky) {
    int hh = h + ky - 1;
    if (hh < 0 || hh >= 128) continue;
    #pragma unroll
    for (int kx = 0; kx < 3; ++kx) {
      int ww = w + kx - 1;
      if (ww < 0 || ww >= 128) continue;
      acc += xb[hh * 128 + ww] * stem_w[c * 9 + ky * 3 + kx];
    }
  }
  state[pos * 64 + c] = fmaxf(acc, 0.f);
}

// ---------------- up1: conv3x3 64->64 + relu (NHWC, LDS patch staging) ----------------
__global__ __launch_bounds__(256) void up1_kernel(const float* __restrict__ state,
                                                  float* __restrict__ hidden,
                                                  const float* __restrict__ wT1,
                                                  const float* __restrict__ up1_b) {
  __shared__ float patch[100 * 64];   // 10x10 spatial halo tile x 64 ch, 25.6 KB
  int blk = blockIdx.x;
  int b = blk >> 8; int tile = blk & 255;
  int h0 = (tile >> 4) * 8; int w0 = (tile & 15) * 8;
  int t = threadIdx.x;
  for (int idx = t; idx < 6400; idx += 256) {
    int pp = idx >> 6, ci = idx & 63;
    int pr = pp / 10, pc = pp - pr * 10;
    int hh = h0 + pr - 1, ww = w0 + pc - 1;
    float v = 0.f;
    if (hh >= 0 && hh < 128 && ww >= 0 && ww < 128)
      v = state[((b << 14) + hh * 128 + ww) * 64 + ci];
    patch[pp * 64 + ci] = v;
  }
  __syncthreads();
  int c = t & 63, wv = t >> 6;
  float acc[16];
  #pragma unroll
  for (int i = 0; i < 16; ++i) acc[i] = 0.f;
  int r0 = wv * 2;                       // each wave owns 2 rows of the 8x8 tile
  for (int tap = 0; tap < 9; ++tap) {
    int ky = tap / 3, kx = tap - ky * 3;
    const float* wrow = wT1 + tap * 4096 + c;
    int base0 = ((r0 + ky) * 10 + kx) * 64;   // row r0 (broadcast addr, no c)
    int base1 = base0 + 640;                  // row r0+1
    for (int ci = 0; ci < 64; ++ci) {
      float wgt = wrow[ci * 64];
      #pragma unroll
      for (int i = 0; i < 8; ++i) acc[i]     += patch[base0 + i * 64 + ci] * wgt;
      #pragma unroll
      for (int i = 0; i < 8; ++i) acc[i + 8] += patch[base1 + i * 64 + ci] * wgt;
    }
  }
  float bb = up1_b[c];
  #pragma unroll
  for (int i = 0; i < 16; ++i) {
    int r = r0 + (i >> 3), cc = i & 7;
    int n = (b << 14) + (h0 + r) * 128 + (w0 + cc);
    hidden[n * 64 + c] = fmaxf(acc[i] + bb, 0.f);
  }
}

// ---------------- fused: up2(1x1) + tau(1x1) + gated update + VQ + loss partials ----------------
__global__ __launch_bounds__(256) void update_vq_kernel(float* __restrict__ state,
      const float* __restrict__ hidden, const float* __restrict__ wT2,
      const float* __restrict__ wTt, const float* __restrict__ up2_b,
      const float* __restrict__ tau_b, const float* __restrict__ cb,
      const float* __restrict__ cbsq, float* __restrict__ partials) {
  __shared__ float smem[12352];   // hid[4096] | stt[4096] | zT[64*65]; cbT aliases [0..4351]
  __shared__ int   bk[64];
  __shared__ float red[4];
  float* hid = smem;              // [pos][k]
  float* stt = smem + 4096;       // [pos][k]
  float* zT  = smem + 8192;       // [c][65] padded
  float* cbT = smem;              // [c][68] padded, reuses hid/stt space in VQ phase

  int blk = blockIdx.x; int n0 = blk * 64; int t = threadIdx.x;
  for (int idx = t; idx < 4096; idx += 256) {
    int p = idx >> 6;
    hid[idx] = hidden[(n0 + p) * 64 + (idx & 63)];
    stt[idx] = state [(n0 + p) * 64 + (idx & 63)];
  }
  __syncthreads();

  int c = t & 63, wv = t >> 6;
  float da[16], ta[16];
  #pragma unroll
  for (int i = 0; i < 16; ++i) { da[i] = 0.f; ta[i] = 0.f; }
  for (int k = 0; k < 64; ++k) {
    float wu = wT2[k * 64 + c];
    float wt = wTt[k * 64 + c];
    int pb = wv * 16 * 64 + k;
    #pragma unroll
    for (int i = 0; i < 16; ++i) {
      da[i] += hid[pb + i * 64] * wu;    // broadcast LDS reads
      ta[i] += stt[pb + i * 64] * wt;
    }
  }
  float bu = up2_b[c], bt = tau_b[c];
  #pragma unroll
  for (int i = 0; i < 16; ++i) {
    int p = wv * 16 + i;
    float beta = 1.f / (1.f + expf(-(ta[i] + bt)));
    float z = beta * stt[p * 64 + c] + (1.f - beta) * (da[i] + bu);
    zT[c * 65 + p] = z;
  }
  __syncthreads();   // zT ready; hid/stt no longer needed

  // VQ: block-tiled scores s = |c|^2 - 2 z.c ; argmin with first-index tie-break
  int ty = t >> 4, tx = t & 15;
  int p0 = ty * 4;
  float bd[4]; int bki[4];
  #pragma unroll
  for (int i = 0; i < 4; ++i) { bd[i] = 1e30f; bki[i] = 0; }
  for (int ch = 0; ch < 8; ++ch) {
    __syncthreads();   // previous chunk's readers done before restaging cbT
    for (int idx = t; idx < 4096; idx += 256) {
      int kk = idx >> 6, cc2 = idx & 63;
      cbT[cc2 * 68 + kk] = cb[(ch * 64 + kk) * 64 + cc2];
    }
    __syncthreads();
    float acc[4][4];
    #pragma unroll
    for (int i = 0; i < 4; ++i)
      #pragma unroll
      for (int j = 0; j < 4; ++j) acc[i][j] = 0.f;
    for (int cc2 = 0; cc2 < 64; ++cc2) {
      float zv[4], cv[4];
      #pragma unroll
      for (int i = 0; i < 4; ++i) zv[i] = zT[cc2 * 65 + p0 + i];
      #pragma unroll
      for (int j = 0; j < 4; ++j) cv[j] = cbT[cc2 * 68 + tx * 4 + j];
      #pragma unroll
      for (int i = 0; i < 4; ++i)
        #pragma unroll
        for (int j = 0; j < 4; ++j) acc[i][j] += zv[i] * cv[j];
    }
    #pragma unroll
    for (int i = 0; i < 4; ++i)
      #pragma unroll
      for (int j = 0; j < 4; ++j) {
        int k = ch * 64 + tx * 4 + j;
        float s = cbsq[k] - 2.f * acc[i][j];
        if (s < bd[i]) { bd[i] = s; bki[i] = k; }
      }
  }
  #pragma unroll
  for (int i = 0; i < 4; ++i) {
    float d = bd[i]; int k = bki[i];
    #pragma unroll
    for (int off = 8; off >= 1; off >>= 1) {
      float od = __shfl_xor(d, off);
      int   ok = __shfl_xor(k, off);
      if (od < d || (od == d && ok < k)) { d = od; k = ok; }
    }
    if (tx == 0) bk[p0 + i] = k;
  }
  __syncthreads();

  // gather z_q, write state in place (block-local), accumulate loss
  float ls = 0.f;
  for (int i = 0; i < 16; ++i) {
    int p = wv * 16 + i;
    int k = bk[p];
    float zq = cb[k * 64 + c];
    float z = zT[c * 65 + p];
    float d = zq - z;
    ls += d * d;
    state[(n0 + p) * 64 + c] = zq;
  }
  #pragma unroll
  for (int off = 32; off >= 1; off >>= 1) ls += __shfl_xor(ls, off);
  if ((t & 63) == 0) red[wv] = ls;
  __syncthreads();
  if (t == 0) partials[blk] = red[0] + red[1] + red[2] + red[3];
}

// ---------------- deterministic loss reduce (per step) ----------------
__global__ void reduce_kernel(const float* __restrict__ partials, float* __restrict__ loss) {
  __shared__ float s[256];
  int t = threadIdx.x;
  float v = 0.f;
  for (int i = t; i < 4096; i += 256) v += partials[i];
  s[t] = v;
  __syncthreads();
  for (int w = 128; w >= 1; w >>= 1) {
    if (t < w) s[t] += s[t + w];
    __syncthreads();
  }
  if (t == 0) loss[0] += s[0];
}

// ---------------- dec: 1x1 64->1 + sigmoid, plus loss scalar ----------------
__global__ void dec_kernel(const float* __restrict__ state, const float* __restrict__ dec_w,
                           const float* __restrict__ dec_b, const float* __restrict__ loss,
                           float* __restrict__ out) {
  int t = threadIdx.x;
  int c = t & 63, wv = t >> 6;
  int n0 = blockIdx.x * 256 + wv * 64;
  float wd = dec_w[c];
  float b0 = dec_b[0];
  for (int p = 0; p < 64; ++p) {
    int n = n0 + p;
    float v = state[n * 64 + c] * wd;
    #pragma unroll
    for (int off = 32; off >= 1; off >>= 1) v += __shfl_xor(v, off);
    if (c == 0) out[n] = 1.f / (1.f + expf(-(v + b0)));
  }
  if (blockIdx.x == 0 && t == 0)
    out[NPOS] = loss[0] * 1.25f / 16777216.f / 5.f;   // (codebook + 0.25*commit), mean, /n_steps
}

extern "C" void kernel_launch(void* const* d_in, const int* in_sizes, int n_in,
                              void* d_out, int out_size, void* d_ws, size_t ws_size,
                              hipStream_t stream) {
  (void)in_sizes; (void)n_in; (void)out_size; (void)ws_size;
  const float* x      = (const float*)d_in[0];
  const float* stem_w = (const float*)d_in[1];
  const float* stem_b = (const float*)d_in[2];
  const float* up1_w  = (const float*)d_in[3];
  const float* up1_b  = (const float*)d_in[4];
  const float* up2_w  = (const float*)d_in[5];
  const float* up2_b  = (const float*)d_in[6];
  const float* tau_w  = (const float*)d_in[7];
  const float* tau_b  = (const float*)d_in[8];
  const float* cb     = (const float*)d_in[9];
  const float* dec_w  = (const float*)d_in[10];
  const float* dec_b  = (const float*)d_in[11];
  // d_in[12] = n_steps (device scalar, fixed = 5; launch sequence must be static for graph capture)
  float* out = (float*)d_out;
  float* ws  = (float*)d_ws;

  prep_kernel<<<179, 256, 0, stream>>>(up1_w, up2_w, tau_w, cb, ws);
  stem_kernel<<<65536, 256, 0, stream>>>(x, stem_w, stem_b, ws + OFF_STATE);
  for (int s = 0; s < NSTEPS; ++s) {
    up1_kernel<<<4096, 256, 0, stream>>>(ws + OFF_STATE, ws + OFF_HIDDEN,
                                         ws + OFF_WUP1, up1_b);
    update_vq_kernel<<<4096, 256, 0, stream>>>(ws + OFF_STATE, ws + OFF_HIDDEN,
        ws + OFF_WUP2, ws + OFF_WTAU, up2_b, tau_b, cb, ws + OFF_CBSQ, ws + OFF_PART);
    reduce_kernel<<<1, 256, 0, stream>>>(ws + OFF_PART, ws + OFF_LOSS);
  }
  dec_kernel<<<1024, 256, 0, stream>>>(ws + OFF_STATE, dec_w, dec_b,
                                       ws + OFF_LOSS, out);
}

// Round 2
// 1538.626 us; speedup vs baseline: 3.4286x; 3.4286x over previous
//
#include <hip/hip_runtime.h>
#include <math.h>

#define NB 16
#define NHH 128
#define NWW 128
#define NPOS (NB*NHH*NWW)      // 262144
#define NSTEPS 5

typedef unsigned short ushort_t;
typedef __attribute__((ext_vector_type(8))) short short8;
typedef __attribute__((ext_vector_type(4))) float f32x4;
#define MFMA __builtin_amdgcn_mfma_f32_16x16x32_bf16

// workspace byte offsets
#define OB_STATE  0u                      // bf16 [NPOS][64]  = 32 MB
#define OB_HIDDEN (32u<<20)               // bf16 [NPOS][64]  = 32 MB
#define OB_W1     (64u<<20)               // bf16 [9][64][64] ([tap][co][ci])
#define OB_W2     (OB_W1 + 73728u)        // bf16 [64][64]    ([co][ci])
#define OB_WT     (OB_W2 + 8192u)         // bf16 [64][64]
#define OB_CBB    (OB_WT + 8192u)         // bf16 [512][64]
#define OB_CBSQ   (OB_CBB + 65536u)       // f32  [512]
#define OB_PART   (OB_CBSQ + 2048u)       // f32  [4096]
#define OB_LOSS   (OB_PART + 16384u)      // f32  [1]

static __device__ __forceinline__ ushort_t f2bf(float f) {
  unsigned u = __float_as_uint(f);
  unsigned r = (u + 0x7fffu + ((u >> 16) & 1u)) >> 16;   // RNE
  return (ushort_t)r;
}
static __device__ __forceinline__ float bf2f(ushort_t h) {
  return __uint_as_float(((unsigned)h) << 16);
}

// ---------------- prep: bf16 weight transposes + codebook + loss init ----------------
__global__ void prep_kernel(const float* __restrict__ up1_w, const float* __restrict__ up2_w,
                            const float* __restrict__ tau_w, const float* __restrict__ cb,
                            char* __restrict__ ws) {
  int id = blockIdx.x * 256 + threadIdx.x;
  ushort_t* w1b = (ushort_t*)(ws + OB_W1);
  ushort_t* w2b = (ushort_t*)(ws + OB_W2);
  ushort_t* wtb = (ushort_t*)(ws + OB_WT);
  ushort_t* cbb = (ushort_t*)(ws + OB_CBB);
  float*   cbsq = (float*)(ws + OB_CBSQ);
  if (id < 36864) {                       // [tap][co][ci] from OIHW [co][ci][3][3]
    int tap = id / 4096; int r = id - tap * 4096; int co = r >> 6; int ci = r & 63;
    w1b[id] = f2bf(up1_w[(co * 64 + ci) * 9 + tap]);
  } else if (id < 40960) {
    int j = id - 36864; w2b[j] = f2bf(up2_w[j]);        // already [co][ci]
  } else if (id < 45056) {
    int j = id - 40960; wtb[j] = f2bf(tau_w[j]);
  } else if (id < 77824) {
    int j = id - 45056; cbb[j] = f2bf(cb[j]);           // [k][ci]
  } else if (id < 78336) {
    int k = id - 77824;
    float s = 0.f;
    for (int c = 0; c < 64; ++c) { float v = cb[k * 64 + c]; s += v * v; }
    cbsq[k] = s;
  } else if (id == 78336) {
    *(float*)(ws + OB_LOSS) = 0.f;
  }
}

// ---------------- stem: conv3x3 1->64 + relu -> bf16 NHWC state ----------------
__global__ void stem_kernel(const float* __restrict__ x, const float* __restrict__ stem_w,
                            const float* __restrict__ stem_b, ushort_t* __restrict__ state) {
  int n = blockIdx.x * 256 + threadIdx.x;
  int pos = n >> 6, c = n & 63;
  int b = pos >> 14, hw = pos & 16383, h = hw >> 7, w = hw & 127;
  const float* xb = x + b * 16384;
  float acc = stem_b[c];
  #pragma unroll
  for (int ky = 0; ky < 3; ++ky) {
    int hh = h + ky - 1;
    if (hh < 0 || hh >= 128) continue;
    #pragma unroll
    for (int kx = 0; kx < 3; ++kx) {
      int ww = w + kx - 1;
      if (ww < 0 || ww >= 128) continue;
      acc += xb[hh * 128 + ww] * stem_w[c * 9 + ky * 3 + kx];
    }
  }
  state[pos * 64 + c] = f2bf(fmaxf(acc, 0.f));
}

// ---------------- up1: conv3x3 64->64 + relu via implicit-GEMM MFMA ----------------
// Block = one image row (128 positions), 4 waves; wave owns 32 positions (2 m-frags).
__global__ __launch_bounds__(256) void up1_kernel(const ushort_t* __restrict__ state,
      ushort_t* __restrict__ hidden, const ushort_t* __restrict__ w1b,
      const float* __restrict__ up1_b) {
  int blk = blockIdx.x;                 // 2048 = 16 * 128
  int b = blk >> 7, h = blk & 127;
  int t = threadIdx.x, lane = t & 63, wv = t >> 6;
  int col = lane & 15, kg = lane >> 4;
  f32x4 acc[2][4] = {};                 // [mf][nf]
  int m0 = wv * 32 + col;               // pos (w coord) of m-frag 0; frag1 = +16
  #pragma unroll
  for (int tap = 0; tap < 9; ++tap) {
    int ky = tap / 3, kx = tap - ky * 3;
    int h2 = h + ky - 1;
    bool hok = (h2 >= 0) && (h2 < 128);
    int w20 = m0 + kx - 1;
    int w21 = w20 + 16;
    bool ok0 = hok && (w20 >= 0) && (w20 < 128);
    bool ok1 = hok && (w21 < 128);      // w21 >= 16-1 >= 0 always
    const ushort_t* row = state + ((b * 128 + h2) * 128) * 64 + kg * 8;
    const ushort_t* wb  = w1b + (tap * 64 + col) * 64 + kg * 8;
    #pragma unroll
    for (int s = 0; s < 2; ++s) {
      short8 a0 = {}; short8 a1 = {};
      if (ok0) a0 = *(const short8*)(row + w20 * 64 + s * 32);
      if (ok1) a1 = *(const short8*)(row + w21 * 64 + s * 32);
      #pragma unroll
      for (int nf = 0; nf < 4; ++nf) {
        short8 bf = *(const short8*)(wb + nf * 1024 + s * 32);
        acc[0][nf] = MFMA(a0, bf, acc[0][nf], 0, 0, 0);
        acc[1][nf] = MFMA(a1, bf, acc[1][nf], 0, 0, 0);
      }
    }
  }
  int nbase = (b * 128 + h) * 128;
  #pragma unroll
  for (int mf = 0; mf < 2; ++mf) {
    int p = wv * 32 + mf * 16 + 4 * kg;
    #pragma unroll
    for (int nf = 0; nf < 4; ++nf) {
      int co = nf * 16 + col;
      float bb = up1_b[co];
      #pragma unroll
      for (int r = 0; r < 4; ++r) {
        float v = fmaxf(acc[mf][nf][r] + bb, 0.f);
        hidden[(nbase + p + r) * 64 + co] = f2bf(v);
      }
    }
  }
}

// ---------------- fused: up2 + tau + gated update + VQ + loss (MFMA) ----------------
// Block = 64 positions, 4 waves; wave owns 16 position-rows.
__global__ __launch_bounds__(256) void update_vq_kernel(ushort_t* __restrict__ state,
      const ushort_t* __restrict__ hidden, const ushort_t* __restrict__ w2b,
      const ushort_t* __restrict__ wtb, const float* __restrict__ up2_b,
      const float* __restrict__ tau_b, const float* __restrict__ cb,
      const ushort_t* __restrict__ cbb, const float* __restrict__ cbsq,
      float* __restrict__ partials) {
  __shared__ ushort_t zl[64 * 72];      // padded: row stride 144B -> 2-way (free) on b128
  __shared__ int bk[64];
  __shared__ float red[4];
  int blk = blockIdx.x; int n0 = blk * 64;
  int t = threadIdx.x, lane = t & 63, wv = t >> 6;
  int col = lane & 15, kg = lane >> 4;

  // phase 1: delta = hid@w2, tauv = stt@wt  (M=16/wave, N=64, K=64)
  int mrow = wv * 16 + col;
  const ushort_t* hrow = hidden + (n0 + mrow) * 64 + kg * 8;
  const ushort_t* srow = state  + (n0 + mrow) * 64 + kg * 8;
  f32x4 accd[4] = {}; f32x4 acct[4] = {};
  #pragma unroll
  for (int s = 0; s < 2; ++s) {
    short8 ah = *(const short8*)(hrow + s * 32);
    short8 as = *(const short8*)(srow + s * 32);
    #pragma unroll
    for (int nf = 0; nf < 4; ++nf) {
      short8 b2 = *(const short8*)(w2b + (nf * 16 + col) * 64 + kg * 8 + s * 32);
      short8 bt = *(const short8*)(wtb + (nf * 16 + col) * 64 + kg * 8 + s * 32);
      accd[nf] = MFMA(ah, b2, accd[nf], 0, 0, 0);
      acct[nf] = MFMA(as, bt, acct[nf], 0, 0, 0);
    }
  }

  // phase 2: z = beta*state + (1-beta)*delta  (lane holds pos=wv*16+4*kg+r, co=nf*16+col)
  float zreg[4][4];
  #pragma unroll
  for (int nf = 0; nf < 4; ++nf) {
    int co = nf * 16 + col;
    float bu = up2_b[co], bt = tau_b[co];
    #pragma unroll
    for (int r = 0; r < 4; ++r) {
      int p = wv * 16 + 4 * kg + r;
      float sval = bf2f(state[(n0 + p) * 64 + co]);
      float beta = 1.f / (1.f + expf(-(acct[nf][r] + bt)));
      float z = beta * sval + (1.f - beta) * (accd[nf][r] + bu);
      zreg[nf][r] = z;
      zl[p * 72 + co] = f2bf(z);
    }
  }
  __syncthreads();

  // phase 3: scores = |c|^2 - 2 z.c over 512 codes; per-lane running argmin
  short8 az0 = *(const short8*)(&zl[(wv * 16 + col) * 72 + kg * 8]);
  short8 az1 = *(const short8*)(&zl[(wv * 16 + col) * 72 + 32 + kg * 8]);
  float bd[4] = {1e30f, 1e30f, 1e30f, 1e30f};
  int bki[4] = {0, 0, 0, 0};
  for (int ch = 0; ch < 32; ++ch) {
    const ushort_t* cbrow = cbb + (ch * 16 + col) * 64 + kg * 8;
    short8 b0 = *(const short8*)(cbrow);
    short8 b1 = *(const short8*)(cbrow + 32);
    f32x4 acc = {};
    acc = MFMA(az0, b0, acc, 0, 0, 0);
    acc = MFMA(az1, b1, acc, 0, 0, 0);
    int code = ch * 16 + col;
    float cs = cbsq[code];
    #pragma unroll
    for (int r = 0; r < 4; ++r) {
      float sc = cs - 2.f * acc[r];
      if (sc < bd[r]) { bd[r] = sc; bki[r] = code; }
    }
  }
  #pragma unroll
  for (int r = 0; r < 4; ++r) {
    float d = bd[r]; int k = bki[r];
    #pragma unroll
    for (int off = 1; off < 16; off <<= 1) {   // reduce across the 16-lane col group
      float od = __shfl_xor(d, off);
      int   ok = __shfl_xor(k, off);
      if (od < d || (od == d && ok < k)) { d = od; k = ok; }
    }
    if (col == 0) bk[wv * 16 + kg * 4 + r] = k;
  }
  __syncthreads();

  // phase 4: gather z_q, loss, write state (same lane layout as phase 2)
  float ls = 0.f;
  #pragma unroll
  for (int nf = 0; nf < 4; ++nf) {
    int co = nf * 16 + col;
    #pragma unroll
    for (int r = 0; r < 4; ++r) {
      int p = wv * 16 + 4 * kg + r;
      float zq = cb[bk[p] * 64 + co];
      float dd = zq - zreg[nf][r];
      ls += dd * dd;
      state[(n0 + p) * 64 + co] = f2bf(zq);
    }
  }
  #pragma unroll
  for (int off = 32; off >= 1; off >>= 1) ls += __shfl_xor(ls, off);
  if (lane == 0) red[wv] = ls;
  __syncthreads();
  if (t == 0) partials[blk] = red[0] + red[1] + red[2] + red[3];
}

// ---------------- deterministic loss reduce (per step) ----------------
__global__ void reduce_kernel(const float* __restrict__ partials, float* __restrict__ loss) {
  __shared__ float s[256];
  int t = threadIdx.x;
  float v = 0.f;
  for (int i = t; i < 4096; i += 256) v += partials[i];
  s[t] = v;
  __syncthreads();
  for (int w = 128; w >= 1; w >>= 1) {
    if (t < w) s[t] += s[t + w];
    __syncthreads();
  }
  if (t == 0) loss[0] += s[0];
}

// ---------------- dec: 1x1 64->1 + sigmoid ----------------
__global__ __launch_bounds__(256) void dec_kernel(const ushort_t* __restrict__ state,
      const float* __restrict__ dec_w, const float* __restrict__ dec_b,
      const float* __restrict__ loss, float* __restrict__ out) {
  __shared__ float wsm[64];
  int t = threadIdx.x;
  if (t < 64) wsm[t] = dec_w[t];
  __syncthreads();
  int n = blockIdx.x * 256 + t;
  const ushort_t* row = state + n * 64;
  float acc = dec_b[0];
  #pragma unroll
  for (int s = 0; s < 8; ++s) {
    short8 v = *(const short8*)(row + s * 8);
    #pragma unroll
    for (int j = 0; j < 8; ++j) acc += bf2f((ushort_t)v[j]) * wsm[s * 8 + j];
  }
  out[n] = 1.f / (1.f + expf(-acc));
  if (n == 0) out[NPOS] = loss[0] * 1.25f / 16777216.f / 5.f;
}

extern "C" void kernel_launch(void* const* d_in, const int* in_sizes, int n_in,
                              void* d_out, int out_size, void* d_ws, size_t ws_size,
                              hipStream_t stream) {
  (void)in_sizes; (void)n_in; (void)out_size; (void)ws_size;
  const float* x      = (const float*)d_in[0];
  const float* stem_w = (const float*)d_in[1];
  const float* stem_b = (const float*)d_in[2];
  const float* up1_w  = (const float*)d_in[3];
  const float* up1_b  = (const float*)d_in[4];
  const float* up2_w  = (const float*)d_in[5];
  const float* up2_b  = (const float*)d_in[6];
  const float* tau_w  = (const float*)d_in[7];
  const float* tau_b  = (const float*)d_in[8];
  const float* cb     = (const float*)d_in[9];
  const float* dec_w  = (const float*)d_in[10];
  const float* dec_b  = (const float*)d_in[11];
  float* out = (float*)d_out;
  char*  ws  = (char*)d_ws;

  ushort_t* state  = (ushort_t*)(ws + OB_STATE);
  ushort_t* hidden = (ushort_t*)(ws + OB_HIDDEN);
  ushort_t* w1b    = (ushort_t*)(ws + OB_W1);
  ushort_t* w2b    = (ushort_t*)(ws + OB_W2);
  ushort_t* wtb    = (ushort_t*)(ws + OB_WT);
  ushort_t* cbb    = (ushort_t*)(ws + OB_CBB);
  float*    cbsq   = (float*)(ws + OB_CBSQ);
  float*    part   = (float*)(ws + OB_PART);
  float*    loss   = (float*)(ws + OB_LOSS);

  prep_kernel<<<307, 256, 0, stream>>>(up1_w, up2_w, tau_w, cb, ws);
  stem_kernel<<<65536, 256, 0, stream>>>(x, stem_w, stem_b, state);
  for (int s = 0; s < NSTEPS; ++s) {
    up1_kernel<<<2048, 256, 0, stream>>>(state, hidden, w1b, up1_b);
    update_vq_kernel<<<4096, 256, 0, stream>>>(state, hidden, w2b, wtb,
        up2_b, tau_b, cb, cbb, cbsq, part);
    reduce_kernel<<<1, 256, 0, stream>>>(part, loss);
  }
  dec_kernel<<<1024, 256, 0, stream>>>(state, dec_w, dec_b, loss, out);
}

// Round 3
// 798.799 us; speedup vs baseline: 6.6041x; 1.9262x over previous
//
#include <hip/hip_runtime.h>
#include <hip/hip_bf16.h>
#include <math.h>

typedef unsigned short ushort_t;
typedef __attribute__((ext_vector_type(8))) short short8;
typedef __attribute__((ext_vector_type(4))) float f32x4;
#define MFMA __builtin_amdgcn_mfma_f32_16x16x32_bf16

#define NPOS 262144
#define NSTEPS 5

// workspace byte offsets (guard page before state0; state1/weights serve as high guard)
#define OB_S0   4096u
#define OB_S1   (OB_S0 + 33554432u)
#define OB_W1A  (OB_S1 + 33554432u)       // bf16 [9][64 m][64 slot]
#define OB_W2A  (OB_W1A + 73728u)         // bf16 [64][64]
#define OB_WTA  (OB_W2A + 8192u)          // bf16 [64][64]
#define OB_CBA  (OB_WTA + 8192u)          // bf16 [512][64]
#define OB_NH   (OB_CBA + 65536u)         // f32 [512]  = -0.5*|c|^2
#define OB_PART (OB_NH + 2048u)           // f32 [1024]
#define OB_LOSS (OB_PART + 4096u)         // f32 [1]

// physical slot p = 32s + 8kg + 4u + r  ->  logical channel 32s + 16u + 4kg + r
static __device__ __forceinline__ int permP(int p) {
  return (p & 0x23) | ((p >> 1) & 0x0c) | ((p & 0x4) << 2);
}
static __device__ __forceinline__ ushort_t f2bf(float f) {
  __hip_bfloat16 h = __float2bfloat16(f);
  return *reinterpret_cast<ushort_t*>(&h);
}
static __device__ __forceinline__ float bf2f(ushort_t h) {
  return __uint_as_float(((unsigned)h) << 16);
}

// ---------------- prep: permuted bf16 weights/codebook, -|c|^2/2, loss=0 ----------------
__global__ void prep_kernel(const float* __restrict__ up1_w, const float* __restrict__ up2_w,
                            const float* __restrict__ tau_w, const float* __restrict__ cb,
                            char* __restrict__ ws) {
  int id = blockIdx.x * 256 + threadIdx.x;
  ushort_t* w1a = (ushort_t*)(ws + OB_W1A);
  ushort_t* w2a = (ushort_t*)(ws + OB_W2A);
  ushort_t* wta = (ushort_t*)(ws + OB_WTA);
  ushort_t* cba = (ushort_t*)(ws + OB_CBA);
  float*    nh  = (float*)(ws + OB_NH);
  if (id < 36864) {                       // [tap][m=co][slot] from OIHW
    int tap = id / 4096; int r = id - tap * 4096; int m = r >> 6; int p = r & 63;
    w1a[id] = f2bf(up1_w[(m * 64 + permP(p)) * 9 + tap]);
  } else if (id < 40960) {
    int j = id - 36864; int m = j >> 6, p = j & 63;
    w2a[j] = f2bf(up2_w[m * 64 + permP(p)]);
  } else if (id < 45056) {
    int j = id - 40960; int m = j >> 6, p = j & 63;
    wta[j] = f2bf(tau_w[m * 64 + permP(p)]);
  } else if (id < 77824) {
    int j = id - 45056; int k = j >> 6, p = j & 63;
    cba[j] = f2bf(cb[k * 64 + permP(p)]);
  } else if (id < 78336) {
    int k = id - 77824;
    float s = 0.f;
    for (int c = 0; c < 64; ++c) { float v = cb[k * 64 + c]; s += v * v; }
    nh[k] = -0.5f * s;
  } else if (id == 78336) {
    *(float*)(ws + OB_LOSS) = 0.f;
  }
}

// ---------------- stem: conv3x3 1->64 + relu -> bf16 permuted-channel state ----------------
__global__ void stem_kernel(const float* __restrict__ x, const float* __restrict__ stem_w,
                            const float* __restrict__ stem_b, ushort_t* __restrict__ state) {
  int n = blockIdx.x * 256 + threadIdx.x;
  int pos = n >> 6, slot = n & 63;
  int c = permP(slot);
  int b = pos >> 14, hw = pos & 16383, h = hw >> 7, w = hw & 127;
  const float* xb = x + b * 16384;
  float acc = stem_b[c];
  #pragma unroll
  for (int ky = 0; ky < 3; ++ky) {
    int hh = h + ky - 1;
    if (hh < 0 || hh >= 128) continue;
    #pragma unroll
    for (int kx = 0; kx < 3; ++kx) {
      int ww = w + kx - 1;
      if (ww < 0 || ww >= 128) continue;
      acc += xb[hh * 128 + ww] * stem_w[c * 9 + ky * 3 + kx];
    }
  }
  state[pos * 64 + slot] = f2bf(fmaxf(acc, 0.f));
}

// ---------------- fused step: up1 -> up2/tau -> gated z -> VQ -> state_out + loss ----------------
// Block = 2 image rows (256 pos), 4 waves; wave owns 64 pos of one row (4 n-frags).
__global__ __launch_bounds__(256) void step_kernel(const ushort_t* __restrict__ sin,
      ushort_t* __restrict__ sout, const ushort_t* __restrict__ w1a,
      const ushort_t* __restrict__ w2a, const ushort_t* __restrict__ wta,
      const float* __restrict__ up1_b, const float* __restrict__ up2_b,
      const float* __restrict__ tau_b, const ushort_t* __restrict__ cba,
      const float* __restrict__ nh, float* __restrict__ partials) {
  __shared__ float red[4];
  int bid = blockIdx.x;
  int lb = (bid & 7) * 128 + (bid >> 3);     // XCD-chunked: each XCD gets 2 whole images
  int b = lb >> 6, rp = lb & 63;
  int t = threadIdx.x, lane = t & 63, wv = t >> 6;
  int col = lane & 15, kg = lane >> 4;
  int row = rp * 2 + (wv >> 1);
  int wseg = (wv & 1) * 64;
  const ushort_t* imgbase = sin + (size_t)b * 1048576u;

  // ---- up1: D1 = W1 . state^T  (m=co, n=pos), K=576 over taps ----
  f32x4 acc1[4][4] = {};                     // [pf][f]
  #pragma unroll
  for (int ky = 0; ky < 3; ++ky) {
    int h2 = row + ky - 1;
    if (h2 < 0 || h2 > 127) continue;        // wave-uniform
    const ushort_t* rptr = imgbase + h2 * 8192;
    #pragma unroll
    for (int kx = 0; kx < 3; ++kx) {
      short8 sbf[4][2];
      #pragma unroll
      for (int pf = 0; pf < 4; ++pf) {
        int wloc = wseg + 16 * pf + col + kx - 1;
        const ushort_t* pp = rptr + wloc * 64 + 8 * kg;
        sbf[pf][0] = *(const short8*)(pp);
        sbf[pf][1] = *(const short8*)(pp + 32);
        if ((kx == 0 && pf == 0) || (kx == 2 && pf == 3)) {
          if ((unsigned)wloc >= 128u) {
            short8 z8 = {};
            sbf[pf][0] = z8; sbf[pf][1] = z8;
          }
        }
      }
      int tap = ky * 3 + kx;
      #pragma unroll
      for (int s = 0; s < 2; ++s) {
        #pragma unroll
        for (int f = 0; f < 4; ++f) {
          short8 a = *(const short8*)(w1a + (tap * 64 + 16 * f + col) * 64 + 32 * s + 8 * kg);
          #pragma unroll
          for (int pf = 0; pf < 4; ++pf)
            acc1[pf][f] = MFMA(a, sbf[pf][s], acc1[pf][f], 0, 0, 0);
        }
      }
    }
  }

  // ---- hidden = relu(D1 + b1), packed to B-frag layout (identity: slot p <-> f=2s+u,r) ----
  f32x4 b1v[4];
  #pragma unroll
  for (int f = 0; f < 4; ++f) b1v[f] = *(const f32x4*)(up1_b + 16 * f + 4 * kg);
  short8 hb[4][2];
  #pragma unroll
  for (int pf = 0; pf < 4; ++pf) {
    #pragma unroll
    for (int s = 0; s < 2; ++s) {
      short8 v;
      #pragma unroll
      for (int u = 0; u < 2; ++u) {
        int f = 2 * s + u;
        #pragma unroll
        for (int r = 0; r < 4; ++r) {
          float h = fmaxf(acc1[pf][f][r] + b1v[f][r], 0.f);
          v[4 * u + r] = (short)f2bf(h);
        }
      }
      hb[pf][s] = v;
    }
  }

  // ---- up2/tau (per pf to bound registers) + gated z, pack zhat ----
  short8 zb[4][2];
  #pragma unroll
  for (int pf = 0; pf < 4; ++pf) {
    int wloc = wseg + 16 * pf + col;
    const ushort_t* cp = imgbase + row * 8192 + wloc * 64 + 8 * kg;
    short8 c0 = *(const short8*)(cp);
    short8 c1 = *(const short8*)(cp + 32);
    f32x4 d2[4] = {}, dt[4] = {};
    #pragma unroll
    for (int s = 0; s < 2; ++s) {
      short8 cs = s ? c1 : c0;
      #pragma unroll
      for (int f = 0; f < 4; ++f) {
        short8 wa2 = *(const short8*)(w2a + (16 * f + col) * 64 + 32 * s + 8 * kg);
        short8 wat = *(const short8*)(wta + (16 * f + col) * 64 + 32 * s + 8 * kg);
        d2[f] = MFMA(wa2, hb[pf][s], d2[f], 0, 0, 0);
        dt[f] = MFMA(wat, cs, dt[f], 0, 0, 0);
      }
    }
    #pragma unroll
    for (int s = 0; s < 2; ++s) {
      short8 cs = s ? c1 : c0;
      short8 zv;
      #pragma unroll
      for (int u = 0; u < 2; ++u) {
        int f = 2 * s + u;
        f32x4 b2 = *(const f32x4*)(up2_b + 16 * f + 4 * kg);
        f32x4 bt = *(const f32x4*)(tau_b + 16 * f + 4 * kg);
        #pragma unroll
        for (int r = 0; r < 4; ++r) {
          float sv = bf2f((ushort_t)cs[4 * u + r]);
          float xg = dt[f][r] + bt[r];
          float beta = __builtin_amdgcn_rcpf(1.f + __expf(-xg));
          float z = beta * sv + (1.f - beta) * (d2[f][r] + b2[r]);
          zv[4 * u + r] = (short)f2bf(z);
        }
      }
      zb[pf][s] = zv;
    }
  }

  // ---- VQ: maximize (z.c - |c|^2/2) == argmin distance; C-init = -|c|^2/2 ----
  float bd[4] = {-3.0e38f, -3.0e38f, -3.0e38f, -3.0e38f};
  int bki[4] = {0, 0, 0, 0};
  #pragma unroll 2
  for (int cf = 0; cf < 32; ++cf) {
    f32x4 cinit = *(const f32x4*)(nh + 16 * cf + 4 * kg);
    const ushort_t* ap = cba + (16 * cf + col) * 64 + 8 * kg;
    short8 a0 = *(const short8*)(ap);
    short8 a1 = *(const short8*)(ap + 32);
    #pragma unroll
    for (int pf = 0; pf < 4; ++pf) {
      f32x4 acc = cinit;
      acc = MFMA(a0, zb[pf][0], acc, 0, 0, 0);
      acc = MFMA(a1, zb[pf][1], acc, 0, 0, 0);
      #pragma unroll
      for (int r = 0; r < 4; ++r) {
        int code = 16 * cf + 4 * kg + r;
        if (acc[r] > bd[pf]) { bd[pf] = acc[r]; bki[pf] = code; }
      }
    }
  }

  // ---- cross-kg argmin, z_q gather (copy codebook rows), store, loss ----
  float ls = 0.f;
  ushort_t* outbase = sout + (size_t)b * 1048576u + row * 8192;
  #pragma unroll
  for (int pf = 0; pf < 4; ++pf) {
    float d = bd[pf]; int k = bki[pf];
    #pragma unroll
    for (int off = 16; off <= 32; off <<= 1) {
      float od = __shfl_xor(d, off);
      int   ok = __shfl_xor(k, off);
      if (od > d || (od == d && ok < k)) { d = od; k = ok; }
    }
    const ushort_t* cr = cba + k * 64 + 8 * kg;
    short8 q0 = *(const short8*)(cr);
    short8 q1 = *(const short8*)(cr + 32);
    ushort_t* op = outbase + (wseg + 16 * pf + col) * 64 + 8 * kg;
    *(short8*)(op) = q0;
    *(short8*)(op + 32) = q1;
    #pragma unroll
    for (int s = 0; s < 2; ++s) {
      short8 q = s ? q1 : q0;
      short8 zv = zb[pf][s];
      #pragma unroll
      for (int j = 0; j < 8; ++j) {
        float dd = bf2f((ushort_t)q[j]) - bf2f((ushort_t)zv[j]);
        ls += dd * dd;
      }
    }
  }
  #pragma unroll
  for (int off = 1; off < 64; off <<= 1) ls += __shfl_xor(ls, off);
  if (lane == 0) red[wv] = ls;
  __syncthreads();
  if (t == 0) partials[bid] = red[0] + red[1] + red[2] + red[3];
}

// ---------------- deterministic loss reduce (per step) ----------------
__global__ void reduce_kernel(const float* __restrict__ partials, float* __restrict__ loss) {
  __shared__ float s[256];
  int t = threadIdx.x;
  float v = 0.f;
  for (int i = t; i < 1024; i += 256) v += partials[i];
  s[t] = v;
  __syncthreads();
  for (int w = 128; w >= 1; w >>= 1) {
    if (t < w) s[t] += s[t + w];
    __syncthreads();
  }
  if (t == 0) loss[0] += s[0];
}

// ---------------- dec: 1x1 64->1 + sigmoid (permuted weights) ----------------
__global__ __launch_bounds__(256) void dec_kernel(const ushort_t* __restrict__ state,
      const float* __restrict__ dec_w, const float* __restrict__ dec_b,
      const float* __restrict__ loss, float* __restrict__ out) {
  __shared__ float wsm[64];
  int t = threadIdx.x;
  if (t < 64) wsm[t] = dec_w[permP(t)];
  __syncthreads();
  int n = blockIdx.x * 256 + t;
  const ushort_t* row = state + (size_t)n * 64;
  float acc = dec_b[0];
  #pragma unroll
  for (int s = 0; s < 8; ++s) {
    short8 v = *(const short8*)(row + s * 8);
    #pragma unroll
    for (int j = 0; j < 8; ++j) acc += bf2f((ushort_t)v[j]) * wsm[s * 8 + j];
  }
  out[n] = __builtin_amdgcn_rcpf(1.f + __expf(-acc));
  if (n == 0) out[NPOS] = loss[0] * 1.25f / (16777216.f * 5.f);
}

extern "C" void kernel_launch(void* const* d_in, const int* in_sizes, int n_in,
                              void* d_out, int out_size, void* d_ws, size_t ws_size,
                              hipStream_t stream) {
  (void)in_sizes; (void)n_in; (void)out_size; (void)ws_size;
  const float* x      = (const float*)d_in[0];
  const float* stem_w = (const float*)d_in[1];
  const float* stem_b = (const float*)d_in[2];
  const float* up1_w  = (const float*)d_in[3];
  const float* up1_b  = (const float*)d_in[4];
  const float* up2_w  = (const float*)d_in[5];
  const float* up2_b  = (const float*)d_in[6];
  const float* tau_w  = (const float*)d_in[7];
  const float* tau_b  = (const float*)d_in[8];
  const float* cb     = (const float*)d_in[9];
  const float* dec_w  = (const float*)d_in[10];
  const float* dec_b  = (const float*)d_in[11];
  float* out = (float*)d_out;
  char*  ws  = (char*)d_ws;

  ushort_t* s0   = (ushort_t*)(ws + OB_S0);
  ushort_t* s1   = (ushort_t*)(ws + OB_S1);
  ushort_t* w1a  = (ushort_t*)(ws + OB_W1A);
  ushort_t* w2a  = (ushort_t*)(ws + OB_W2A);
  ushort_t* wta  = (ushort_t*)(ws + OB_WTA);
  ushort_t* cba  = (ushort_t*)(ws + OB_CBA);
  float*    nh   = (float*)(ws + OB_NH);
  float*    part = (float*)(ws + OB_PART);
  float*    loss = (float*)(ws + OB_LOSS);

  prep_kernel<<<307, 256, 0, stream>>>(up1_w, up2_w, tau_w, cb, ws);
  stem_kernel<<<65536, 256, 0, stream>>>(x, stem_w, stem_b, s0);
  for (int s = 0; s < NSTEPS; ++s) {
    const ushort_t* in  = (s & 1) ? s1 : s0;
    ushort_t*       o   = (s & 1) ? s0 : s1;
    step_kernel<<<1024, 256, 0, stream>>>(in, o, w1a, w2a, wta,
        up1_b, up2_b, tau_b, cba, nh, part);
    reduce_kernel<<<1, 256, 0, stream>>>(part, loss);
  }
  dec_kernel<<<1024, 256, 0, stream>>>(s1, dec_w, dec_b, loss, out);
}

// Round 4
// 394.857 us; speedup vs baseline: 13.3601x; 2.0230x over previous
//
#include <hip/hip_runtime.h>
#include <hip/hip_bf16.h>
#include <math.h>

typedef unsigned short ushort_t;
typedef __attribute__((ext_vector_type(8))) short short8;
typedef __attribute__((ext_vector_type(4))) float f32x4;
typedef __attribute__((ext_vector_type(4))) int int4v;
#define MFMA __builtin_amdgcn_mfma_f32_16x16x32_bf16

#define NPOS 262144
#define NSTEPS 5

// workspace byte offsets (guard page before state0 for wloc=-1 halo loads)
#define OB_S0   4096u
#define OB_S1   (OB_S0 + 33554432u)
#define OB_STG  (OB_S1 + 33554432u)       // 157696 B staged region: [w1f|w2f|wtf|cbf|nh]
#define STG_W2  73728u
#define STG_WT  81920u
#define STG_CB  90112u
#define STG_NH  155648u
#define STG_SZ  157696u
#define OB_SWT  (OB_STG + STG_SZ)         // f32 [9][64] stem weights (permuted slots)
#define OB_SBP  (OB_SWT + 2304u)          // f32 [64] stem bias (permuted)
#define OB_PART (OB_SBP + 256u)           // f32 [5][512]
#define DYN_LDS 157760u                   // staged 157696 + red[8] floats + pad

// physical slot p = 32s + 8kg + 4u + r  ->  logical channel 32s + 16u + 4kg + r
static __device__ __forceinline__ int permP(int p) {
  return (p & 0x23) | ((p >> 1) & 0x0c) | ((p & 0x4) << 2);
}
static __device__ __forceinline__ ushort_t f2bf(float f) {
  __hip_bfloat16 h = __float2bfloat16(f);
  return *reinterpret_cast<ushort_t*>(&h);
}
static __device__ __forceinline__ float bf2f(ushort_t h) {
  return __uint_as_float(((unsigned)h) << 16);
}

// ---------------- prep: fragment-major bf16 weights/codebook + stem tables ----------------
__global__ void prep_kernel(const float* __restrict__ up1_w, const float* __restrict__ up2_w,
                            const float* __restrict__ tau_w, const float* __restrict__ cb,
                            const float* __restrict__ stem_w, const float* __restrict__ stem_b,
                            char* __restrict__ ws) {
  int id = blockIdx.x * 256 + threadIdx.x;
  ushort_t* stg = (ushort_t*)(ws + OB_STG);
  if (id < 36864) {                       // w1f: [tap][s][f][lane][j]
    int j = id & 7, lane = (id >> 3) & 63, f = (id >> 9) & 3, s = (id >> 11) & 1, tap = id >> 12;
    int col = lane & 15, kg = lane >> 4;
    stg[id] = f2bf(up1_w[((16 * f + col) * 64 + permP(32 * s + 8 * kg + j)) * 9 + tap]);
  } else if (id < 40960) {                // w2f: [s][f][lane][j]
    int jj = id - 36864;
    int j = jj & 7, lane = (jj >> 3) & 63, f = (jj >> 9) & 3, s = (jj >> 11) & 1;
    int col = lane & 15, kg = lane >> 4;
    stg[id] = f2bf(up2_w[(16 * f + col) * 64 + permP(32 * s + 8 * kg + j)]);
  } else if (id < 45056) {                // wtf
    int jj = id - 40960;
    int j = jj & 7, lane = (jj >> 3) & 63, f = (jj >> 9) & 3, s = (jj >> 11) & 1;
    int col = lane & 15, kg = lane >> 4;
    stg[id] = f2bf(tau_w[(16 * f + col) * 64 + permP(32 * s + 8 * kg + j)]);
  } else if (id < 77824) {                // cbf: [cf][s][lane][j]
    int jj = id - 45056;
    int j = jj & 7, lane = (jj >> 3) & 63, s = (jj >> 9) & 1, cf = jj >> 10;
    int col = lane & 15, kg = lane >> 4;
    stg[id] = f2bf(cb[(16 * cf + col) * 64 + permP(32 * s + 8 * kg + j)]);
  } else if (id < 78336) {                // nh = -0.5*|c|^2
    int k = id - 77824;
    float s = 0.f;
    for (int c = 0; c < 64; ++c) { float v = cb[k * 64 + c]; s += v * v; }
    ((float*)(ws + OB_STG + STG_NH))[k] = -0.5f * s;
  } else if (id < 78912) {                // stem weights [tap][slot]
    int jj = id - 78336; int tap = jj >> 6, slot = jj & 63;
    ((float*)(ws + OB_SWT))[jj] = stem_w[permP(slot) * 9 + tap];
  } else if (id < 78976) {                // stem bias [slot]
    int slot = id - 78912;
    ((float*)(ws + OB_SBP))[slot] = stem_b[permP(slot)];
  }
}

// ---------------- stem: conv3x3 1->64 + relu, thread-per-position ----------------
__global__ __launch_bounds__(256) void stem_kernel(const float* __restrict__ x,
      const char* __restrict__ wsro, ushort_t* __restrict__ state) {
  const float* swt = (const float*)(wsro + OB_SWT);
  const float* sbp = (const float*)(wsro + OB_SBP);
  int pos = blockIdx.x * 256 + threadIdx.x;
  int b = pos >> 14, hw = pos & 16383, h = hw >> 7, w = hw & 127;
  const float* xb = x + b * 16384;
  float xv[9];
  #pragma unroll
  for (int ky = 0; ky < 3; ++ky) {
    #pragma unroll
    for (int kx = 0; kx < 3; ++kx) {
      int hh = h + ky - 1, ww = w + kx - 1;
      bool ok = (hh >= 0) && (hh < 128) && (ww >= 0) && (ww < 128);
      xv[ky * 3 + kx] = ok ? xb[hh * 128 + ww] : 0.f;
    }
  }
  float acc[64];
  #pragma unroll
  for (int i = 0; i < 64; ++i) acc[i] = sbp[i];
  #pragma unroll
  for (int tap = 0; tap < 9; ++tap) {
    float xt = xv[tap];
    #pragma unroll
    for (int g = 0; g < 16; ++g) {
      f32x4 w4 = *(const f32x4*)(swt + tap * 64 + g * 4);
      #pragma unroll
      for (int j = 0; j < 4; ++j) acc[g * 4 + j] += xt * w4[j];
    }
  }
  ushort_t* op = state + (size_t)pos * 64;
  #pragma unroll
  for (int sg = 0; sg < 8; ++sg) {
    short8 o;
    #pragma unroll
    for (int j = 0; j < 8; ++j) o[j] = (short)f2bf(fmaxf(acc[sg * 8 + j], 0.f));
    *(short8*)(op + sg * 8) = o;
  }
}

// ---------------- fused step: LDS-resident weights, 1 block/CU, 2 work-units ----------------
// Block = 512 threads (8 waves). Work-unit = 4 image rows (512 pos); wave owns 64 pos (4 pf).
__global__ __launch_bounds__(512, 2) void step_kernel(const ushort_t* __restrict__ sin,
      ushort_t* __restrict__ sout, const char* __restrict__ wsro,
      const float* __restrict__ up1_b, const float* __restrict__ up2_b,
      const float* __restrict__ tau_b, float* __restrict__ partials) {
  extern __shared__ char smem[];
  int t = threadIdx.x, lane = t & 63, wv = t >> 6;
  int col = lane & 15, kg = lane >> 4;
  float* red = (float*)(smem + STG_SZ);

  // stage all weights/codebook into LDS (linear copy, conflict-free)
  const char* src = wsro + OB_STG;
  for (int it = 0; it < 20; ++it) {
    int c = it * 512 + t;
    if (c < 9856) *(int4v*)(smem + c * 16) = *(const int4v*)(src + c * 16);
  }
  __syncthreads();

  for (int wi = 0; wi < 2; ++wi) {
    int wu = blockIdx.x + wi * 256;
    int lb = ((wu & 7) << 6) + (wu >> 3);     // XCD-chunked: XCD x owns images 2x,2x+1
    int b = lb >> 5;
    int row = (lb & 31) * 4 + (wv >> 1);
    int wseg = (wv & 1) * 64;
    const ushort_t* imgbase = sin + (size_t)b * 1048576u;

    // ---- up1: D = W1 . state^T (m=co, n=pos), A-frags from LDS ----
    f32x4 acc1[4][4] = {};                    // [pf][f]
    #pragma unroll
    for (int ky = 0; ky < 3; ++ky) {
      int h2 = row + ky - 1;
      if (h2 < 0 || h2 > 127) continue;       // wave-uniform
      const ushort_t* rptr = imgbase + h2 * 8192;
      #pragma unroll
      for (int kx = 0; kx < 3; ++kx) {
        short8 sbf[4][2];
        #pragma unroll
        for (int pf = 0; pf < 4; ++pf) {
          int wloc = wseg + 16 * pf + col + kx - 1;
          const ushort_t* pp = rptr + wloc * 64 + 8 * kg;
          sbf[pf][0] = *(const short8*)(pp);
          sbf[pf][1] = *(const short8*)(pp + 32);
          if ((kx == 0 && pf == 0) || (kx == 2 && pf == 3)) {
            if ((unsigned)wloc >= 128u) {
              short8 z8 = {};
              sbf[pf][0] = z8; sbf[pf][1] = z8;
            }
          }
        }
        int tap = ky * 3 + kx;
        #pragma unroll
        for (int s = 0; s < 2; ++s) {
          #pragma unroll
          for (int f = 0; f < 4; ++f) {
            short8 a = *(const short8*)(smem + ((tap * 2 + s) * 4 + f) * 1024 + lane * 16);
            #pragma unroll
            for (int pf = 0; pf < 4; ++pf)
              acc1[pf][f] = MFMA(a, sbf[pf][s], acc1[pf][f], 0, 0, 0);
          }
        }
      }
    }

    // ---- hidden = relu(D1+b1) packed to B-frag layout (slot identity) ----
    f32x4 b1v[4];
    #pragma unroll
    for (int f = 0; f < 4; ++f) b1v[f] = *(const f32x4*)(up1_b + 16 * f + 4 * kg);
    short8 hb[4][2];
    #pragma unroll
    for (int pf = 0; pf < 4; ++pf) {
      #pragma unroll
      for (int s = 0; s < 2; ++s) {
        short8 v;
        #pragma unroll
        for (int u = 0; u < 2; ++u) {
          int f = 2 * s + u;
          #pragma unroll
          for (int r = 0; r < 4; ++r)
            v[4 * u + r] = (short)f2bf(fmaxf(acc1[pf][f][r] + b1v[f][r], 0.f));
        }
        hb[pf][s] = v;
      }
    }

    // ---- up2/tau + gated z, pack zhat (weights from LDS) ----
    short8 zb[4][2];
    #pragma unroll
    for (int pf = 0; pf < 4; ++pf) {
      int wloc = wseg + 16 * pf + col;
      const ushort_t* cp = imgbase + row * 8192 + wloc * 64 + 8 * kg;
      short8 c0 = *(const short8*)(cp);
      short8 c1 = *(const short8*)(cp + 32);
      f32x4 d2[4] = {}, dt[4] = {};
      #pragma unroll
      for (int s = 0; s < 2; ++s) {
        short8 cs = s ? c1 : c0;
        #pragma unroll
        for (int f = 0; f < 4; ++f) {
          short8 wa2 = *(const short8*)(smem + STG_W2 + (s * 4 + f) * 1024 + lane * 16);
          short8 wat = *(const short8*)(smem + STG_WT + (s * 4 + f) * 1024 + lane * 16);
          d2[f] = MFMA(wa2, hb[pf][s], d2[f], 0, 0, 0);
          dt[f] = MFMA(wat, cs, dt[f], 0, 0, 0);
        }
      }
      #pragma unroll
      for (int s = 0; s < 2; ++s) {
        short8 cs = s ? c1 : c0;
        short8 zv;
        #pragma unroll
        for (int u = 0; u < 2; ++u) {
          int f = 2 * s + u;
          f32x4 b2 = *(const f32x4*)(up2_b + 16 * f + 4 * kg);
          f32x4 bt = *(const f32x4*)(tau_b + 16 * f + 4 * kg);
          #pragma unroll
          for (int r = 0; r < 4; ++r) {
            float sv = bf2f((ushort_t)cs[4 * u + r]);
            float xg = dt[f][r] + bt[r];
            float beta = __builtin_amdgcn_rcpf(1.f + __expf(-xg));
            float z = beta * sv + (1.f - beta) * (d2[f][r] + b2[r]);
            zv[4 * u + r] = (short)f2bf(z);
          }
        }
        zb[pf][s] = zv;
      }
    }

    // ---- VQ: argmax (z.c - |c|^2/2), codebook frags from LDS ----
    float bd[4] = {-3.0e38f, -3.0e38f, -3.0e38f, -3.0e38f};
    int bki[4] = {0, 0, 0, 0};
    #pragma unroll 2
    for (int cf = 0; cf < 32; ++cf) {
      short8 a0 = *(const short8*)(smem + STG_CB + (cf * 2 + 0) * 1024 + lane * 16);
      short8 a1 = *(const short8*)(smem + STG_CB + (cf * 2 + 1) * 1024 + lane * 16);
      f32x4 cinit = *(const f32x4*)(smem + STG_NH + (16 * cf + 4 * kg) * 4);
      #pragma unroll
      for (int pf = 0; pf < 4; ++pf) {
        f32x4 acc = cinit;
        acc = MFMA(a0, zb[pf][0], acc, 0, 0, 0);
        acc = MFMA(a1, zb[pf][1], acc, 0, 0, 0);
        #pragma unroll
        for (int r = 0; r < 4; ++r) {
          int code = 16 * cf + 4 * kg + r;
          if (acc[r] > bd[pf]) { bd[pf] = acc[r]; bki[pf] = code; }
        }
      }
    }

    // ---- cross-kg argmax, z_q gather from LDS codebook, store, loss ----
    float ls = 0.f;
    ushort_t* outbase = sout + (size_t)b * 1048576u + row * 8192;
    #pragma unroll
    for (int pf = 0; pf < 4; ++pf) {
      float d = bd[pf]; int k = bki[pf];
      #pragma unroll
      for (int off = 16; off <= 32; off <<= 1) {
        float od = __shfl_xor(d, off);
        int   ok = __shfl_xor(k, off);
        if (od > d || (od == d && ok < k)) { d = od; k = ok; }
      }
      int cbase = STG_CB + ((k >> 4) * 2) * 1024 + (16 * kg + (k & 15)) * 16;
      short8 q0 = *(const short8*)(smem + cbase);
      short8 q1 = *(const short8*)(smem + cbase + 1024);
      ushort_t* op = outbase + (wseg + 16 * pf + col) * 64 + 8 * kg;
      *(short8*)(op) = q0;
      *(short8*)(op + 32) = q1;
      #pragma unroll
      for (int s = 0; s < 2; ++s) {
        short8 q = s ? q1 : q0;
        short8 zv = zb[pf][s];
        #pragma unroll
        for (int j = 0; j < 8; ++j) {
          float dd = bf2f((ushort_t)q[j]) - bf2f((ushort_t)zv[j]);
          ls += dd * dd;
        }
      }
    }
    #pragma unroll
    for (int off = 1; off < 64; off <<= 1) ls += __shfl_xor(ls, off);
    if (lane == 0) red[wv] = ls;
    __syncthreads();
    if (t == 0) {
      float s = 0.f;
      #pragma unroll
      for (int i = 0; i < 8; ++i) s += red[i];
      partials[wu] = s;
    }
    __syncthreads();
  }
}

// ---------------- dec: 1x1 64->1 + sigmoid, coalesced; block 0 reduces loss ----------------
__global__ __launch_bounds__(256) void dec_kernel(const ushort_t* __restrict__ state,
      const float* __restrict__ dec_w, const float* __restrict__ dec_b,
      const float* __restrict__ part, float* __restrict__ out) {
  __shared__ float wsm[64];
  __shared__ float rs[256];
  int t = threadIdx.x;
  if (t < 64) wsm[t] = dec_w[permP(t)];
  __syncthreads();
  int wv = t >> 6, lane = t & 63;
  int pl = lane >> 3, sc = lane & 7;
  float b0 = dec_b[0];
  int base0 = blockIdx.x * 256;
  #pragma unroll
  for (int it = 0; it < 8; ++it) {
    int pos = base0 + it * 32 + wv * 8 + pl;
    short8 v = *(const short8*)(state + (size_t)pos * 64 + sc * 8);
    float d = 0.f;
    #pragma unroll
    for (int j = 0; j < 8; ++j) d += bf2f((ushort_t)v[j]) * wsm[sc * 8 + j];
    d += __shfl_xor(d, 1); d += __shfl_xor(d, 2); d += __shfl_xor(d, 4);
    if (sc == 0) out[pos] = __builtin_amdgcn_rcpf(1.f + __expf(-(d + b0)));
  }
  if (blockIdx.x == 0) {
    float v = 0.f;
    for (int i = t; i < 2560; i += 256) v += part[i];
    rs[t] = v;
    __syncthreads();
    for (int w = 128; w >= 1; w >>= 1) {
      if (t < w) rs[t] += rs[t + w];
      __syncthreads();
    }
    if (t == 0) out[NPOS] = rs[0] * 1.25f / (16777216.f * 5.f);
  }
}

extern "C" void kernel_launch(void* const* d_in, const int* in_sizes, int n_in,
                              void* d_out, int out_size, void* d_ws, size_t ws_size,
                              hipStream_t stream) {
  (void)in_sizes; (void)n_in; (void)out_size; (void)ws_size;
  const float* x      = (const float*)d_in[0];
  const float* stem_w = (const float*)d_in[1];
  const float* stem_b = (const float*)d_in[2];
  const float* up1_w  = (const float*)d_in[3];
  const float* up1_b  = (const float*)d_in[4];
  const float* up2_w  = (const float*)d_in[5];
  const float* up2_b  = (const float*)d_in[6];
  const float* tau_w  = (const float*)d_in[7];
  const float* tau_b  = (const float*)d_in[8];
  const float* cb     = (const float*)d_in[9];
  const float* dec_w  = (const float*)d_in[10];
  const float* dec_b  = (const float*)d_in[11];
  float* out = (float*)d_out;
  char*  ws  = (char*)d_ws;

  ushort_t* s0   = (ushort_t*)(ws + OB_S0);
  ushort_t* s1   = (ushort_t*)(ws + OB_S1);
  float*    part = (float*)(ws + OB_PART);

  (void)hipFuncSetAttribute((const void*)step_kernel,
                            hipFuncAttributeMaxDynamicSharedMemorySize, DYN_LDS);

  prep_kernel<<<309, 256, 0, stream>>>(up1_w, up2_w, tau_w, cb, stem_w, stem_b, ws);
  stem_kernel<<<1024, 256, 0, stream>>>(x, ws, s0);
  for (int s = 0; s < NSTEPS; ++s) {
    const ushort_t* in  = (s & 1) ? s1 : s0;
    ushort_t*       o   = (s & 1) ? s0 : s1;
    step_kernel<<<256, 512, DYN_LDS, stream>>>(in, o, ws, up1_b, up2_b, tau_b,
                                               part + s * 512);
  }
  dec_kernel<<<1024, 256, 0, stream>>>(s1, dec_w, dec_b, part, out);
}